// Round 6
// baseline (138.507 us; speedup 1.0000x reference)
//
#include <hip/hip_runtime.h>
#include <math.h>
#include <float.h>

// Problem constants (from the reference)
#define NN 4096
#define DD 512
#define HD 256                     // half of D
#define HF4 64                     // float4 per half-row (256 floats)
#define PP 8
#define QQ 32
#define NB_TOT 40
#define NPW 5                      // neighbors per wave (8 waves x 5 = 40)
constexpr float MARGIN = 1.0f;
constexpr float L2W    = 0.005f;
constexpr float EPS    = 1e-6f;

// ws layout (floats):
//   [0,            NN*HD)   packed lo halves (4 MB)
//   [NN*HD,      2*NN*HD)   packed hi halves (4 MB)
//   [2*NN*HD, +NN*NB_TOT)   per-pair partial squared distances
//   [.., +NN)               per-anchor partial squared norms
#define WS_LO 0
#define WS_HI (NN * HD)
#define WS_D  (2 * NN * HD)
#define WS_N  (WS_D + NN * NB_TOT)

__device__ inline float wave_reduce_sum(float v) {
    v += __shfl_xor(v, 32, 64);
    v += __shfl_xor(v, 16, 64);
    v += __shfl_xor(v,  8, 64);
    v += __shfl_xor(v,  4, 64);
    v += __shfl_xor(v,  2, 64);
    v += __shfl_xor(v,  1, 64);
    return v;
}

__device__ inline float wave_reduce_max(float v) {
    v = fmaxf(v, __shfl_xor(v, 32, 64));
    v = fmaxf(v, __shfl_xor(v, 16, 64));
    v = fmaxf(v, __shfl_xor(v,  8, 64));
    v = fmaxf(v, __shfl_xor(v,  4, 64));
    v = fmaxf(v, __shfl_xor(v,  2, 64));
    v = fmaxf(v, __shfl_xor(v,  1, 64));
    return v;
}

// Repack batch [NN][512] into two packed half-matrices of 4 MB each so each
// phase's gather working set fits a single XCD L2 (4 MiB). Also zeroes d_out.
// 524288 threads, 1 float4 each; both read and write fully coalesced.
__global__ __launch_bounds__(256) void repack_kernel(
    const float4* __restrict__ batch4,
    float4* __restrict__ lo4,
    float4* __restrict__ hi4,
    float*  __restrict__ out)
{
    const int t   = blockIdx.x * 256 + threadIdx.x;   // 0 .. 524287
    const int row = t >> 7;                           // 128 float4 per row
    const int c   = t & 127;
    const float4 v = batch4[t];
    if (c < HF4) lo4[row * HF4 + c]         = v;
    else         hi4[row * HF4 + (c - HF4)] = v;
    if (t == 0) out[0] = 0.0f;
}

// One block per anchor; 8 waves x 5 neighbors. Each half-row is exactly one
// dwordx4 per wave (64 lanes x 16 B = 1 KB), gathered from the packed 4 MB
// half-matrix (L2-resident). FIN=false: store partial sums. FIN=true: combine,
// sqrt, fused logsumexp epilogue, one atomicAdd per block.
template<bool FIN>
__global__ __launch_bounds__(512) void phase_kernel(
    const float4* __restrict__ half4,     // packed lo or hi [NN*HF4]
    const int*    __restrict__ anchors,
    const int*    __restrict__ pos_idx,
    const int*    __restrict__ neg_idx,
    float*        __restrict__ wsD,       // [NN][NB_TOT] partial sq dists
    float*        __restrict__ wsN,       // [NN] partial sq norms
    float*        __restrict__ out)
{
    const int i    = blockIdx.x;
    const int tid  = threadIdx.x;
    const int lane = tid & 63;
    const int wave = tid >> 6;            // 0..7
    const int jb   = wave * NPW;

    __shared__ float dist[NB_TOT];
    __shared__ float norm_sh;

    // ---- anchor half-row (one float4 per lane) ----
    const int arow = anchors[i];
    float4 a = half4[(size_t)arow * HF4 + lane];

    // ---- wave 7: partial norm of row i (L1-hot: same row as anchor) ----
    if (wave == 7) {
        const float4 r = half4[(size_t)i * HF4 + lane];
        float s = r.x*r.x + r.y*r.y + r.z*r.z + r.w*r.w;
        s = wave_reduce_sum(s);
        if (lane == 0) {
            if (FIN) norm_sh = sqrtf(s + wsN[i]);
            else     wsN[i]  = s;
        }
    }

    // EPS folded into the anchor once (applies per element in both halves)
    a.x += EPS; a.y += EPS; a.z += EPS; a.w += EPS;

    // ---- this wave's 5 neighbor indices (wave-uniform scalar loads) ----
    int idxs[NPW];
    #pragma unroll
    for (int t = 0; t < NPW; ++t) {
        const int j = jb + t;
        idxs[t] = (j < PP) ? pos_idx[i * PP + j] : neg_idx[i * QQ + (j - PP)];
    }

    // ---- 5 half-row gathers in flight (1 KB each, fully coalesced) ----
    float4 b[NPW];
    #pragma unroll
    for (int t = 0; t < NPW; ++t)
        b[t] = half4[(size_t)idxs[t] * HF4 + lane];

    // ---- partial squared distances: 2 VALU/elem ----
    float s[NPW];
    #pragma unroll
    for (int t = 0; t < NPW; ++t) {
        float d, acc = 0.0f;
        d = a.x - b[t].x; acc = fmaf(d, d, acc);
        d = a.y - b[t].y; acc = fmaf(d, d, acc);
        d = a.z - b[t].z; acc = fmaf(d, d, acc);
        d = a.w - b[t].w; acc = fmaf(d, d, acc);
        s[t] = acc;
    }

    #pragma unroll
    for (int t = 0; t < NPW; ++t) s[t] = wave_reduce_sum(s[t]);

    // lanes 0..4 carry the 5 values
    float v = s[0];
    v = (lane == 1) ? s[1] : v;
    v = (lane == 2) ? s[2] : v;
    v = (lane == 3) ? s[3] : v;
    v = (lane == 4) ? s[4] : v;

    if (!FIN) {
        if (lane < NPW) wsD[i * NB_TOT + jb + lane] = v;
        return;
    }

    // ---- FIN: combine with phase-A partials, finish distances ----
    if (lane < NPW)
        dist[jb + lane] = sqrtf(v + wsD[i * NB_TOT + jb + lane]);

    __syncthreads();

    // ---- wave-parallel logsumexp epilogue (lanes 0..39 of wave 0) ----
    if (wave == 0) {
        const float d = (lane < NB_TOT) ? dist[lane] : 0.0f;

        const bool pact = (lane < PP);
        const float pm = wave_reduce_max(pact ? d : -FLT_MAX);
        const float ps = wave_reduce_sum(pact ? expf(d - pm) : 0.0f);
        const float pos_term = pm + logf(ps);

        const bool nact = (lane >= PP) && (lane < NB_TOT);
        const float nv = MARGIN - d;
        const float nm = wave_reduce_max(nact ? nv : -FLT_MAX);
        const float ns = wave_reduce_sum(nact ? expf(nv - nm) : 0.0f);
        const float neg_term = nm + logf(ns);

        if (lane == 0) {
            const float val = fmaxf(0.0f, pos_term + neg_term) + L2W * norm_sh;
            atomicAdd(out, val * (1.0f / (float)NN));
        }
    }
}

extern "C" void kernel_launch(void* const* d_in, const int* in_sizes, int n_in,
                              void* d_out, int out_size, void* d_ws, size_t ws_size,
                              hipStream_t stream) {
    const float*  batch   = (const float*)d_in[0];
    const int*    anchors = (const int*)d_in[1];
    const int*    pos_idx = (const int*)d_in[2];
    const int*    neg_idx = (const int*)d_in[3];
    float*        wsf     = (float*)d_ws;
    float*        out     = (float*)d_out;

    const float4* batch4 = (const float4*)batch;
    float4*       lo4    = (float4*)(wsf + WS_LO);
    float4*       hi4    = (float4*)(wsf + WS_HI);
    float*        wsD    = wsf + WS_D;
    float*        wsN    = wsf + WS_N;

    // 524288 float4 moves -> 2048 blocks x 256
    repack_kernel<<<2048, 256, 0, stream>>>(batch4, lo4, hi4, out);
    phase_kernel<false><<<NN, 512, 0, stream>>>(lo4, anchors, pos_idx, neg_idx,
                                                wsD, wsN, out);
    phase_kernel<true ><<<NN, 512, 0, stream>>>(hi4, anchors, pos_idx, neg_idx,
                                                wsD, wsN, out);
}

// Round 7
// 85.105 us; speedup vs baseline: 1.6275x; 1.6275x over previous
//
#include <hip/hip_runtime.h>
#include <math.h>
#include <float.h>

// Problem constants (from the reference)
#define NN 4096
#define DD 512
#define PP 8
#define QQ 32
#define NB_TOT 40
#define NPW 10                     // neighbors per wave (4 waves x 10 = 40)
constexpr float MARGIN = 1.0f;
constexpr float L2W    = 0.005f;
constexpr float EPS    = 1e-6f;

typedef _Float16 half8 __attribute__((ext_vector_type(8)));

// ws layout (floats):
//   [0, NN*DD/2)             fp16 batch copy (4 MB, NN*DD halves)
//   [NN*DD/2, +NN)           per-row fp32 norms
//   [NN*DD/2+NN, +NN)        per-anchor results
#define WS_NORM (NN * DD / 2)
#define WS_RES  (WS_NORM + NN)

__device__ inline float wave_reduce_sum(float v) {
    v += __shfl_xor(v, 32, 64);
    v += __shfl_xor(v, 16, 64);
    v += __shfl_xor(v,  8, 64);
    v += __shfl_xor(v,  4, 64);
    v += __shfl_xor(v,  2, 64);
    v += __shfl_xor(v,  1, 64);
    return v;
}

__device__ inline float wave_reduce_max(float v) {
    v = fmaxf(v, __shfl_xor(v, 32, 64));
    v = fmaxf(v, __shfl_xor(v, 16, 64));
    v = fmaxf(v, __shfl_xor(v,  8, 64));
    v = fmaxf(v, __shfl_xor(v,  4, 64));
    v = fmaxf(v, __shfl_xor(v,  2, 64));
    v = fmaxf(v, __shfl_xor(v,  1, 64));
    return v;
}

// One wave per row: read 2KB fp32 (coalesced), write 1KB fp16 (coalesced),
// and compute the exact fp32 row norm. 4 rows per 256-thread block.
__global__ __launch_bounds__(256) void convert_kernel(
    const float4* __restrict__ batch4,   // [NN*128]
    half8*        __restrict__ hb,       // [NN*64]
    float*        __restrict__ norms)    // [NN]
{
    const int row  = blockIdx.x * 4 + (threadIdx.x >> 6);
    const int lane = threadIdx.x & 63;

    const float4 v0 = batch4[row * 128 + lane * 2];
    const float4 v1 = batch4[row * 128 + lane * 2 + 1];

    half8 h;
    h[0] = (_Float16)v0.x; h[1] = (_Float16)v0.y;
    h[2] = (_Float16)v0.z; h[3] = (_Float16)v0.w;
    h[4] = (_Float16)v1.x; h[5] = (_Float16)v1.y;
    h[6] = (_Float16)v1.z; h[7] = (_Float16)v1.w;
    hb[row * 64 + lane] = h;

    float s = v0.x*v0.x + v0.y*v0.y + v0.z*v0.z + v0.w*v0.w
            + v1.x*v1.x + v1.y*v1.y + v1.z*v1.z + v1.w*v1.w;
    s = wave_reduce_sum(s);
    if (lane == 0) norms[row] = sqrtf(s);
}

// One block per anchor; 4 waves x 10 neighbors. Each fp16 row is exactly ONE
// dwordx4 per wave (64 lanes x 16 B = 1 KB = 512 halves), so 10 row-requests
// in flight cover 10 full rows. Gather source is the 4 MB fp16 batch
// (L2-resident per XCD). Distances in fp32; eps folded into converted anchor.
__global__ __launch_bounds__(256) void dist_kernel(
    const half8* __restrict__ hb,
    const int*   __restrict__ anchors,
    const int*   __restrict__ pos_idx,
    const int*   __restrict__ neg_idx,
    const float* __restrict__ norms,
    float*       __restrict__ res)
{
    const int i    = blockIdx.x;
    const int tid  = threadIdx.x;
    const int lane = tid & 63;
    const int wave = tid >> 6;            // 0..3
    const int jb   = wave * NPW;

    __shared__ float dist[NB_TOT];

    // ---- anchor row (one request), fp32 + eps ----
    const int arow = anchors[i];
    const half8 ah = hb[(size_t)arow * 64 + lane];
    float a[8];
    #pragma unroll
    for (int k = 0; k < 8; ++k) a[k] = (float)ah[k] + EPS;

    // ---- this wave's 10 neighbor indices (wave-uniform scalar loads) ----
    int idxs[NPW];
    #pragma unroll
    for (int t = 0; t < NPW; ++t) {
        const int j = jb + t;
        idxs[t] = (j < PP) ? pos_idx[i * PP + j] : neg_idx[i * QQ + (j - PP)];
    }

    // ---- all 10 row requests in flight ----
    half8 bh[NPW];
    #pragma unroll
    for (int t = 0; t < NPW; ++t)
        bh[t] = hb[(size_t)idxs[t] * 64 + lane];

    // ---- squared distances in fp32 ----
    float s[NPW];
    #pragma unroll
    for (int t = 0; t < NPW; ++t) {
        float acc = 0.0f;
        #pragma unroll
        for (int k = 0; k < 8; ++k) {
            const float d = a[k] - (float)bh[t][k];
            acc = fmaf(d, d, acc);
        }
        s[t] = acc;
    }

    // ---- 10 independent shuffle-reduce chains ----
    #pragma unroll
    for (int t = 0; t < NPW; ++t) s[t] = wave_reduce_sum(s[t]);

    // ---- lanes 0..9 store the 10 distances ----
    float v = s[0];
    #pragma unroll
    for (int t = 1; t < NPW; ++t) v = (lane == t) ? s[t] : v;
    if (lane < NPW) dist[jb + lane] = sqrtf(v);

    __syncthreads();

    // ---- wave-parallel logsumexp epilogue (lanes 0..39 of wave 0) ----
    if (wave == 0) {
        const float d = (lane < NB_TOT) ? dist[lane] : 0.0f;

        const bool pact = (lane < PP);
        const float pm = wave_reduce_max(pact ? d : -FLT_MAX);
        const float ps = wave_reduce_sum(pact ? expf(d - pm) : 0.0f);
        const float pos_term = pm + logf(ps);

        const bool nact = (lane >= PP) && (lane < NB_TOT);
        const float nv = MARGIN - d;
        const float nm = wave_reduce_max(nact ? nv : -FLT_MAX);
        const float ns = wave_reduce_sum(nact ? expf(nv - nm) : 0.0f);
        const float neg_term = nm + logf(ns);

        if (lane == 0)
            res[i] = fmaxf(0.0f, pos_term + neg_term) + L2W * norms[i];
    }
}

// Single-block final reduction: out = mean(res[0..N))
__global__ __launch_bounds__(256) void reduce_kernel(
    const float* __restrict__ res, float* __restrict__ out)
{
    const int tid  = threadIdx.x;
    const int lane = tid & 63;
    const int wave = tid >> 6;

    const float4* __restrict__ w4 = reinterpret_cast<const float4*>(res);
    float s = 0.0f;
    #pragma unroll
    for (int k = 0; k < 4; ++k) {          // 1024 float4 total
        const float4 v = w4[tid + 256 * k];
        s += v.x + v.y + v.z + v.w;
    }
    s = wave_reduce_sum(s);

    __shared__ float part[4];
    if (lane == 0) part[wave] = s;
    __syncthreads();
    if (tid == 0)
        out[0] = (part[0] + part[1] + part[2] + part[3]) * (1.0f / (float)NN);
}

extern "C" void kernel_launch(void* const* d_in, const int* in_sizes, int n_in,
                              void* d_out, int out_size, void* d_ws, size_t ws_size,
                              hipStream_t stream) {
    const float* batch   = (const float*)d_in[0];
    const int*   anchors = (const int*)d_in[1];
    const int*   pos_idx = (const int*)d_in[2];
    const int*   neg_idx = (const int*)d_in[3];
    float*       wsf     = (float*)d_ws;
    float*       out     = (float*)d_out;

    half8* hb    = (half8*)wsf;
    float* norms = wsf + WS_NORM;
    float* res   = wsf + WS_RES;

    convert_kernel<<<NN / 4, 256, 0, stream>>>((const float4*)batch, hb, norms);
    dist_kernel<<<NN, 256, 0, stream>>>(hb, anchors, pos_idx, neg_idx, norms, res);
    reduce_kernel<<<1, 256, 0, stream>>>(res, out);
}